// Round 14
// baseline (429.791 us; speedup 1.0000x reference)
//
#include <hip/hip_runtime.h>
#include <math.h>

#define NN   20000
#define TT   32
#define INF_ 32
#define HID  64
#define NH   4
#define EE   320000
#define ETOT (EE + NN)
#define ZRW  328   // shorts/row: 5 chunks x 64 (8 hi + 8 lo per lq-group); 656B = 41 x 16B
#define NB   80    // nodes per LSTM block; 250*80 = 20000 exact
#define SCB  80    // scan blocks (80 x 250 = 20000)

typedef __attribute__((ext_vector_type(8))) short bf16x8;
typedef __attribute__((ext_vector_type(4))) float f32x4;

static __device__ __forceinline__ float lrelu(float x){ return x>0.0f ? x : 0.2f*x; }

static __device__ __forceinline__ unsigned short f2bf(float f){
  unsigned u = __float_as_uint(f);
  unsigned r = u + 0x7fffu + ((u>>16)&1u);
  return (unsigned short)(r>>16);
}
static __device__ __forceinline__ float bf2f(unsigned short h){ return __uint_as_float(((unsigned)h)<<16); }

// chunk-local permuted position for k' (0..31)
static __device__ __forceinline__ int zpos(int kq){
  return (kq&3) + (((kq>>4)&1)<<2) + (((kq>>2)&3)<<3);
}

// fused LSTM cell: 5 exp + 2 rcp
static __device__ __forceinline__ float lstm_cell(float gi, float gf, float gg, float go, float& c){
  float ef = __expf(-gf), ei = __expf(-gi), eg = __expf(-2.0f*gg);
  float pN = c*(1.0f+ei)*(1.0f+eg) + (1.0f-eg)*(1.0f+ef);
  float pD = (1.0f+ef)*(1.0f+ei)*(1.0f+eg);
  float cc = pN * __builtin_amdgcn_rcpf(pD);
  c = cc;
  float eo = __expf(-go), ec = __expf(-2.0f*cc);
  return (1.0f-ec) * __builtin_amdgcn_rcpf((1.0f+eo)*(1.0f+ec));
}

static __device__ __forceinline__ void edge_sd(const int* __restrict__ ei, int e, int& s, int& d){
  if (e < EE){ s = ei[e]; d = ei[EE + e]; } else { s = e - EE; d = s; }
}

// ---------------- utility kernels ----------------
__global__ void kzero_int(int* __restrict__ p, int n){
  int i = blockIdx.x*256 + threadIdx.x;
  if (i < n) p[i] = 0;
}

// Pack weights into MFMA A-frag layout, rows permuted so C/D row = 4*unitLocal + gateType. (verified R9-R12)
__global__ void pack_weights(const float* __restrict__ Wih0, const float* __restrict__ Whh0,
                             const float* __restrict__ bih0, const float* __restrict__ bhh0,
                             const float* __restrict__ Wih1, const float* __restrict__ Whh1,
                             const float* __restrict__ bih1, const float* __restrict__ bhh1,
                             unsigned short* __restrict__ Wpk,
                             float* __restrict__ b0, float* __restrict__ b1){
  int idx = blockIdx.x*256 + threadIdx.x;
  if (idx < 49152){
    int fb = idx >> 9;            // (tl*3+ks)*2+h
    int h  = fb & 1;
    int t2 = fb >> 1;
    int ks = t2 % 3, tl = t2 / 3;
    int r  = idx & 511;
    int l  = r >> 3, j = r & 7;
    int pr = l & 15;
    int g  = (pr&3)*64 + tl*4 + (pr>>2);
    int k  = ks*32 + 4*(l>>4) + (j & 3) + 16*(j >> 2);
    float src = (k < 32) ? Wih0[g*32 + k] : Whh0[g*64 + (k - 32)];
    unsigned short hi = f2bf(src);
    Wpk[idx] = h ? f2bf(src - bf2f(hi)) : hi;
  } else if (idx < 114688){
    int idx2 = idx - 49152;
    int fb = idx2 >> 9;           // (tl*4+ks)*2+h
    int h  = fb & 1;
    int t2 = fb >> 1;
    int ks = t2 & 3, tl = t2 >> 2;
    int r  = idx2 & 511;
    int l  = r >> 3, j = r & 7;
    int pr = l & 15;
    int g  = (pr&3)*64 + tl*4 + (pr>>2);
    int k  = ks*32 + 4*(l>>4) + (j & 3) + 16*(j >> 2);
    float src = (k < 64) ? Wih1[g*64 + k] : Whh1[g*64 + (k - 64)];
    unsigned short hi = f2bf(src);
    Wpk[idx] = h ? f2bf(src - bf2f(hi)) : hi;
  } else {
    int m = idx - 114688;
    if (m < 256) b0[m] = bih0[m] + bhh0[m];
    else if (m < 512) b1[m-256] = bih1[m-256] + bhh1[m-256];
  }
}

// ---------------- CSR build (dst-indexed), parallel scan ----------------
__global__ void count_deg(const int* __restrict__ ei, int* __restrict__ deg){
  int e = blockIdx.x*256 + threadIdx.x;
  if (e >= ETOT) return;
  int s, d; edge_sd(ei, e, s, d);
  atomicAdd(deg + d, 1);
}

__global__ void scan_part(const int* __restrict__ deg, int* __restrict__ part){
  __shared__ int s[256];
  const int b = blockIdx.x, t = threadIdx.x;
  int v = (t < 250) ? deg[b*250 + t] : 0;
  s[t] = v; __syncthreads();
  for (int off=128; off>=1; off>>=1){ if (t<off) s[t]+=s[t+off]; __syncthreads(); }
  if (t==0) part[b] = s[0];
}

__global__ void scan_tops(int* __restrict__ part){
  if (threadIdx.x==0){
    int run=0;
    for (int i=0;i<SCB;i++){ int v=part[i]; part[i]=run; run+=v; }
  }
}

__global__ void scan_fill(const int* __restrict__ deg, const int* __restrict__ part,
                          int* __restrict__ indptr, int* __restrict__ cursor){
  __shared__ int s[256];
  const int b = blockIdx.x, t = threadIdx.x;
  int v = (t < 250) ? deg[b*250 + t] : 0;
  s[t] = v; __syncthreads();
  int val = v;
  for (int off=1; off<256; off<<=1){
    int add = (t>=off) ? s[t-off] : 0;
    __syncthreads();
    val += add; s[t] = val;
    __syncthreads();
  }
  int excl = val - v + part[b];
  if (t < 250){ indptr[b*250 + t] = excl; cursor[b*250 + t] = excl; }
  if (b == SCB-1 && t == 0) indptr[NN] = ETOT;
}

__global__ void scatter_edges(const int* __restrict__ ei, int* __restrict__ cursor, int* __restrict__ csr_src){
  int e = blockIdx.x*256 + threadIdx.x;
  if (e >= ETOT) return;
  int s, d; edge_sd(ei, e, s, d);
  int pos = atomicAdd(cursor + d, 1);
  csr_src[pos] = s;
}

// pin a 16B weight fragment into VGPRs
#define PIN_LOAD(dst, p) asm volatile( \
    "global_load_dwordx4 %0, %1, off\n\t" \
    "s_waitcnt vmcnt(0)" \
    : "=&v"(dst) : "v"(p))

// ---------------- MFMA split-bf16 2-layer LSTM: role-split waves (anti-lockstep) ----------------
// grpB=(w>>2)&1 gives 2+2 waves per SIMD running phases in OPPOSITE order:
// while group A issues MFMA chunks, group B runs VALU cells, then swap.
__global__ __launch_bounds__(1024)
__attribute__((amdgpu_waves_per_eu(4, 4)))
void lstm_mfma(
    const float* __restrict__ x,
    const unsigned short* __restrict__ Wpk,
    const float* __restrict__ b0, const float* __restrict__ b1,
    float* __restrict__ h1out)
{
  __shared__ unsigned short Zc[NB*ZRW];   // 52.5 KB

  const int tid  = threadIdx.x;
  const int lane = tid & 63;
  const int w    = __builtin_amdgcn_readfirstlane(tid >> 6);   // 0..15
  const int ln15 = lane & 15;
  const int lq   = lane >> 4;                                  // 0..3
  const int grpB = (w >> 2) & 1;                               // SIMD gets 2A+2B
  const int gbase = blockIdx.x * NB;

  const bf16x8* wp = (const bf16x8*)Wpk;

  bf16x8 wA0h[3], wA0l[3], wA1h[4], wA1l[4];
#pragma unroll
  for (int ks=0; ks<3; ++ks){
    PIN_LOAD(wA0h[ks], wp + ((w*3+ks)*2+0)*64 + lane);
    PIN_LOAD(wA0l[ks], wp + ((w*3+ks)*2+1)*64 + lane);
  }
#pragma unroll
  for (int ks=0; ks<4; ++ks){
    PIN_LOAD(wA1h[ks], wp + 6144 + ((w*4+ks)*2+0)*64 + lane);
    PIN_LOAD(wA1l[ks], wp + 6144 + ((w*4+ks)*2+1)*64 + lane);
  }

  f32x4 bv0, bv1;
  {
    const int u = w*4 + lq;
#pragma unroll
    for (int j=0; j<4; ++j){ bv0[j] = b0[j*64+u]; bv1[j] = b1[j*64+u]; }
  }

  // H-write hi-columns for unit u = w*4+lq (lo at +8)
  const int colbase = ((w&3)<<4) + lq + (((w>>2)&1)<<2);
  const int uc0 = (1 + (w>>3))*64 + colbase;   // h0 chunk
  const int uc1 = (3 + (w>>3))*64 + colbase;   // h1 chunk

  // x staging: threads 0..639
  const int xn = tid >> 3;
  const int xk = (tid & 7) * 4;
  const int p0 = (((xk>>4)&1)<<2) + (((xk>>2)&3)<<3);
  const int xoff = ((p0>>3)<<4) + (p0&7);
  const float* xp = x + (size_t)(gbase + ((xn < NB) ? xn : 0))*(TT*INF_) + xk;
  const bool xth = (tid < 640);

#define XSTAGE(v) {                                                       \
    unsigned pkA, pkB, plA, plB;                                          \
    asm("v_cvt_pk_bf16_f32 %0,%1,%2":"=v"(pkA):"v"((v).x),"v"((v).y));    \
    asm("v_cvt_pk_bf16_f32 %0,%1,%2":"=v"(pkB):"v"((v).z),"v"((v).w));    \
    float l0_ = (v).x - __uint_as_float(pkA<<16);                         \
    float l1_ = (v).y - __uint_as_float(pkA & 0xffff0000u);               \
    float l2_ = (v).z - __uint_as_float(pkB<<16);                         \
    float l3_ = (v).w - __uint_as_float(pkB & 0xffff0000u);               \
    asm("v_cvt_pk_bf16_f32 %0,%1,%2":"=v"(plA):"v"(l0_),"v"(l1_));        \
    asm("v_cvt_pk_bf16_f32 %0,%1,%2":"=v"(plB):"v"(l2_),"v"(l3_));        \
    *(uint2*)&Zc[xn*ZRW + xoff]     = make_uint2(pkA, pkB);               \
    *(uint2*)&Zc[xn*ZRW + xoff + 8] = make_uint2(plA, plB); }

  for (int i = tid; i < NB*ZRW/2; i += 1024) ((unsigned*)Zc)[i] = 0;
  __syncthreads();
  if (xth){
    float4 v = *(const float4*)xp;
    XSTAGE(v);
  }
  __syncthreads();

  float c0[5], c1[5];
#pragma unroll
  for (int i=0;i<5;i++){ c0[i]=0.f; c1[i]=0.f; }
  f32x4 aL1[5];

#define MF(acc, A, B) acc = __builtin_amdgcn_mfma_f32_16x16x32_bf16((A),(B),(acc),0,0,0)

#define WPAIR(ha, hb, GA, GB, colh) {                                     \
    unsigned pk_, pl_;                                                    \
    asm("v_cvt_pk_bf16_f32 %0,%1,%2":"=v"(pk_):"v"(ha),"v"(hb));          \
    float la_ = (ha) - __uint_as_float(pk_<<16);                          \
    float lb_ = (hb) - __uint_as_float(pk_ & 0xffff0000u);                \
    asm("v_cvt_pk_bf16_f32 %0,%1,%2":"=v"(pl_):"v"(la_),"v"(lb_));        \
    Zc[((GA)*16+ln15)*ZRW + (colh)]     = (unsigned short)pk_;            \
    Zc[((GB)*16+ln15)*ZRW + (colh)]     = (unsigned short)(pk_>>16);      \
    Zc[((GA)*16+ln15)*ZRW + (colh) + 8] = (unsigned short)pl_;            \
    Zc[((GB)*16+ln15)*ZRW + (colh) + 8] = (unsigned short)(pl_>>16); }

#define WSINGLE(hv, GG, colh) {                                           \
    const int _n = (GG)*16 + ln15;                                        \
    const unsigned short _hh = f2bf(hv);                                  \
    Zc[_n*ZRW + (colh)]     = _hh;                                        \
    Zc[_n*ZRW + (colh) + 8] = f2bf((hv) - bf2f(_hh)); }

#define CHUNK(ACCS, CK, WH, WL)                                           \
    _Pragma("unroll")                                                     \
    for (int GG=0; GG<5; ++GG){                                           \
      const int nd_ = GG*16 + ln15;                                       \
      const bf16x8 zh = *(const bf16x8*)&Zc[nd_*ZRW + (CK)*64 + lq*16];   \
      const bf16x8 zl = *(const bf16x8*)&Zc[nd_*ZRW + (CK)*64 + lq*16+8]; \
      MF(ACCS[GG], WH, zh); MF(ACCS[GG], WH, zl); MF(ACCS[GG], WL, zh);   \
    }

#define CELLS(ACC, CARR, COLH) {                                          \
    float h0_ = lstm_cell(ACC[0][0], ACC[0][1], ACC[0][2], ACC[0][3], CARR[0]); \
    float h1_ = lstm_cell(ACC[1][0], ACC[1][1], ACC[1][2], ACC[1][3], CARR[1]); \
    float h2_ = lstm_cell(ACC[2][0], ACC[2][1], ACC[2][2], ACC[2][3], CARR[2]); \
    float h3_ = lstm_cell(ACC[3][0], ACC[3][1], ACC[3][2], ACC[3][3], CARR[3]); \
    float h4_ = lstm_cell(ACC[4][0], ACC[4][1], ACC[4][2], ACC[4][3], CARR[4]); \
    WPAIR(h0_, h1_, 0, 1, COLH); WPAIR(h2_, h3_, 2, 3, COLH); WSINGLE(h4_, 4, COLH); }

#define L0CHUNKS { __builtin_amdgcn_s_setprio(1);                         \
    CHUNK(aL0, 0, wA0h[0], wA0l[0]);                                      \
    CHUNK(aL0, 1, wA0h[1], wA0l[1]);                                      \
    CHUNK(aL0, 2, wA0h[2], wA0l[2]);                                      \
    __builtin_amdgcn_s_setprio(0); }

#define L1CHUNKS34 { __builtin_amdgcn_s_setprio(1);                       \
    CHUNK(aL1, 3, wA1h[2], wA1l[2]);                                      \
    CHUNK(aL1, 4, wA1h[3], wA1l[3]);                                      \
    __builtin_amdgcn_s_setprio(0); }

  for (int t=0; t<TT; ++t){
    // ====== P1: L0 chunks (0,1,2) + L1-cells(t-1)->H1, order split by group ======
    float4 xv;
    const bool dox = xth && (t+1 < TT);
    if (dox) xv = *(const float4*)(xp + (size_t)(t+1)*INF_);

    f32x4 aL0[5];
#pragma unroll
    for (int GG=0; GG<5; ++GG) aL0[GG] = bv0;

    if (!grpB){
      L0CHUNKS;
      if (t > 0) CELLS(aL1, c1, uc1);
    } else {
      if (t > 0) CELLS(aL1, c1, uc1);
      L0CHUNKS;
    }
    __syncthreads();

    // ====== P2: L1 chunks (3,4) + L0-cells->H0 + x(t+1) write, order split ======
#pragma unroll
    for (int GG=0; GG<5; ++GG) aL1[GG] = bv1;

    if (!grpB){
      CELLS(aL0, c0, uc0);
      if (dox) XSTAGE(xv);
      L1CHUNKS34;
    } else {
      L1CHUNKS34;
      CELLS(aL0, c0, uc0);
      if (dox) XSTAGE(xv);
    }
    __syncthreads();

    // ====== P3: L1 chunks 1,2 (H0 just written) — no trailing barrier ======
    __builtin_amdgcn_s_setprio(1);
    CHUNK(aL1, 1, wA1h[0], wA1l[0]);
    CHUNK(aL1, 2, wA1h[1], wA1l[1]);
    __builtin_amdgcn_s_setprio(0);
  }

  // final L1 cells -> H1
  CELLS(aL1, c1, uc1);
  __syncthreads();

  // epilogue: coalesced h1 write
  for (int o = tid; o < NB*64; o += 1024){
    const int n = o >> 6, u = o & 63;
    const int p = zpos(u & 31);
    const int ch = (3 + (u>>5))*64 + ((p>>3)<<4) + (p&7);
    h1out[(size_t)(gbase+n)*64 + u] = bf2f(Zc[n*ZRW + ch]) + bf2f(Zc[n*ZRW + ch + 8]);
  }
#undef MF
#undef WPAIR
#undef WSINGLE
#undef CHUNK
#undef CELLS
#undef L0CHUNKS
#undef L1CHUNKS34
#undef XSTAGE
}

// ---------------- GAT layer 1 prep: 32 nodes/block ----------------
__global__ __launch_bounds__(256) void gat1_prep(const float* __restrict__ h1, const float* __restrict__ W,
  const float* __restrict__ as_, const float* __restrict__ ad_,
  float* __restrict__ xh, float* __restrict__ als, float* __restrict__ ald)
{
  __shared__ float hs[32][64];
  const int nb0 = blockIdx.x * 32;
  const int o  = threadIdx.x;
  const int q  = o >> 6, u = o & 63;
  for (int i = o; i < 2048; i += 256){
    hs[i>>6][i&63] = h1[(size_t)(nb0 + (i>>6))*64 + (i&63)];
  }
  __syncthreads();
  float acc[32];
#pragma unroll
  for (int nd=0; nd<32; ++nd) acc[nd] = 0.f;
  for (int k=0; k<64; ++k){
    const float wv = W[k*256 + o];
#pragma unroll
    for (int nd=0; nd<32; ++nd) acc[nd] = fmaf(hs[nd][k], wv, acc[nd]);
  }
  const float asv = as_[o], adv = ad_[o];
#pragma unroll
  for (int nd=0; nd<32; ++nd){
    xh[(size_t)(nb0+nd)*256 + o] = acc[nd];
    float ps = acc[nd] * asv;
    float pd = acc[nd] * adv;
#pragma unroll
    for (int off=32; off>=1; off>>=1){ ps += __shfl_xor(ps, off); pd += __shfl_xor(pd, off); }
    if (u == 0){ als[(nb0+nd)*4 + q] = ps; ald[(nb0+nd)*4 + q] = pd; }
  }
}

// ---------------- GAT1 gather + fused epilogue ----------------
__global__ __launch_bounds__(256) void gat1_gather(
  const int* __restrict__ indptr, const int* __restrict__ csr_src,
  const float* __restrict__ als, const float* __restrict__ ald,
  const float* __restrict__ xh,  const float* __restrict__ b1g,
  const float* __restrict__ w2,  const float* __restrict__ as2, const float* __restrict__ ad2,
  float* __restrict__ xh2, float* __restrict__ a2s, float* __restrict__ a2d)
{
  const int d = blockIdx.x*4 + (threadIdx.x >> 6);
  const int lane = threadIdx.x & 63;
  if (d >= NN) return;
  const int p0 = indptr[d], p1 = indptr[d+1];

  float aldv[4];
#pragma unroll
  for (int q=0;q<4;q++) aldv[q] = ald[d*4+q];

  float mx[4];
#pragma unroll
  for (int q=0;q<4;q++) mx[q] = -3.4e38f;
  for (int e=p0+lane; e<p1; e+=64){
    int s = csr_src[e];
#pragma unroll
    for (int q=0;q<4;q++){
      float ev = lrelu(als[s*4+q] + aldv[q]);
      mx[q] = fmaxf(mx[q], ev);
    }
  }
#pragma unroll
  for (int off=32; off>=1; off>>=1){
#pragma unroll
    for (int q=0;q<4;q++) mx[q] = fmaxf(mx[q], __shfl_xor(mx[q], off));
  }

  const int q = lane >> 4;
  const float mq = mx[q];
  const float aldq = aldv[q];
  float ax=0.f, ay=0.f, az=0.f, aw=0.f, den=0.f;
  int s_next = (p0 < p1) ? csr_src[p0] : 0;
  for (int e=p0; e<p1; ++e){
    const int s = s_next;
    if (e+1 < p1) s_next = csr_src[e+1];
    float ev = lrelu(als[s*4+q] + aldq);
    float ex = __expf(ev - mq);
    den += ex;
    float4 v = *(const float4*)(xh + (size_t)s*256 + lane*4);
    ax = fmaf(ex, v.x, ax); ay = fmaf(ex, v.y, ay);
    az = fmaf(ex, v.z, az); aw = fmaf(ex, v.w, aw);
  }
  const float rr = 1.0f/(den + 1e-16f);
  const int o = lane*4;
  float v0 = ax*rr + b1g[o+0];
  float v1 = ay*rr + b1g[o+1];
  float v2 = az*rr + b1g[o+2];
  float v3 = aw*rr + b1g[o+3];
  v0 = v0>0.f?v0:0.f; v1 = v1>0.f?v1:0.f; v2 = v2>0.f?v2:0.f; v3 = v3>0.f?v3:0.f;
  float part = v0*w2[o+0] + v1*w2[o+1] + v2*w2[o+2] + v3*w2[o+3];
#pragma unroll
  for (int off=32; off>=1; off>>=1) part += __shfl_xor(part, off);
  if (lane == 0){
    xh2[d] = part;
    a2s[d] = part * as2[0];
    a2d[d] = part * ad2[0];
  }
}

// ---------------- GAT2 gather ----------------
__global__ __launch_bounds__(256) void gat2_gather(
  const int* __restrict__ indptr, const int* __restrict__ csr_src,
  const float* __restrict__ a2s, const float* __restrict__ a2d,
  const float* __restrict__ xh2, const float* __restrict__ b2,
  float* __restrict__ out)
{
  const int d = blockIdx.x*4 + (threadIdx.x >> 6);
  const int lane = threadIdx.x & 63;
  if (d >= NN) return;
  const int p0 = indptr[d], p1 = indptr[d+1];
  const float add = a2d[d];

  float mx = -3.4e38f;
  for (int e=p0+lane; e<p1; e+=64){
    int s = csr_src[e];
    mx = fmaxf(mx, lrelu(a2s[s] + add));
  }
#pragma unroll
  for (int off=32; off>=1; off>>=1) mx = fmaxf(mx, __shfl_xor(mx, off));

  float den = 0.f, num = 0.f;
  for (int e=p0+lane; e<p1; e+=64){
    int s = csr_src[e];
    float ev = lrelu(a2s[s] + add);
    float ex = __expf(ev - mx);
    den += ex;
    num = fmaf(ex, xh2[s], num);
  }
#pragma unroll
  for (int off=32; off>=1; off>>=1){ den += __shfl_xor(den, off); num += __shfl_xor(num, off); }
  if (lane == 0) out[d] = num/(den + 1e-16f) + b2[0];
}

// ---------------- launcher ----------------
extern "C" void kernel_launch(void* const* d_in, const int* in_sizes, int n_in,
                              void* d_out, int out_size, void* d_ws, size_t ws_size,
                              hipStream_t stream)
{
  const float* x    = (const float*)d_in[0];
  const int*   ei   = (const int*)d_in[1];
  const float* Wih0 = (const float*)d_in[2];
  const float* Whh0 = (const float*)d_in[3];
  const float* bih0 = (const float*)d_in[4];
  const float* bhh0 = (const float*)d_in[5];
  const float* Wih1 = (const float*)d_in[6];
  const float* Whh1 = (const float*)d_in[7];
  const float* bih1 = (const float*)d_in[8];
  const float* bhh1 = (const float*)d_in[9];
  const float* g1w  = (const float*)d_in[10];
  const float* g1as = (const float*)d_in[11];
  const float* g1ad = (const float*)d_in[12];
  const float* g1b  = (const float*)d_in[13];
  const float* g2w  = (const float*)d_in[14];
  const float* g2as = (const float*)d_in[15];
  const float* g2ad = (const float*)d_in[16];
  const float* g2b  = (const float*)d_in[17];

  float* ws  = (float*)d_ws;
  unsigned short* Wpk = (unsigned short*)ws;   // 114688 shorts = 57344 f32 slots
  float* b0  = ws + 57344;            // 256
  float* b1  = b0 + 256;              // 256
  float* h1  = b1 + 256;              // 20000*64
  float* xh  = h1 + 1280000;          // 20000*256
  float* als = xh + 5120000;          // 80000
  float* ald = als + 80000;           // 80000
  float* xh2 = ald + 80000;           // 20000
  float* a2s = xh2 + 20000;           // 20000
  float* a2d = a2s + 20000;           // 20000
  int*   deg    = (int*)(a2d + 20000);   // 20000
  int*   indptr = deg + 20000;           // 20001
  int*   cursor = indptr + 20001;        // 20000
  int*   csr    = cursor + 20000;        // 340000
  int*   spart  = csr + 340000;          // 80

  kzero_int<<<(NN+255)/256, 256, 0, stream>>>(deg, NN);
  pack_weights<<<450, 256, 0, stream>>>(Wih0,Whh0,bih0,bhh0,Wih1,Whh1,bih1,bhh1,Wpk,b0,b1);
  count_deg<<<(ETOT+255)/256, 256, 0, stream>>>(ei, deg);
  scan_part<<<SCB, 256, 0, stream>>>(deg, spart);
  scan_tops<<<1, 64, 0, stream>>>(spart);
  scan_fill<<<SCB, 256, 0, stream>>>(deg, spart, indptr, cursor);
  scatter_edges<<<(ETOT+255)/256, 256, 0, stream>>>(ei, cursor, csr);
  lstm_mfma<<<250, 1024, 0, stream>>>(x, Wpk, b0, b1, h1);
  gat1_prep<<<NN/32, 256, 0, stream>>>(h1, g1w, g1as, g1ad, xh, als, ald);
  gat1_gather<<<(NN+3)/4, 256, 0, stream>>>(indptr, csr, als, ald, xh, g1b, g2w, g2as, g2ad, xh2, a2s, a2d);
  gat2_gather<<<(NN+3)/4, 256, 0, stream>>>(indptr, csr, a2s, a2d, xh2, g2b, (float*)d_out);
}

// Round 15
// 357.914 us; speedup vs baseline: 1.2008x; 1.2008x over previous
//
#include <hip/hip_runtime.h>
#include <math.h>

#define NN   20000
#define TT   32
#define INF_ 32
#define HID  64
#define NH   4
#define EE   320000
#define ETOT (EE + NN)
#define ZRW  328   // shorts/row: 5 chunks x 64 (8 hi + 8 lo per lq-group); 656B = 41 x 16B
#define NB   80    // nodes per LSTM block; 250*80 = 20000 exact
#define SCB  80    // scan blocks (80 x 250 = 20000)

typedef __attribute__((ext_vector_type(8))) short bf16x8;
typedef __attribute__((ext_vector_type(4))) float f32x4;

static __device__ __forceinline__ float lrelu(float x){ return x>0.0f ? x : 0.2f*x; }

static __device__ __forceinline__ unsigned short f2bf(float f){
  unsigned u = __float_as_uint(f);
  unsigned r = u + 0x7fffu + ((u>>16)&1u);
  return (unsigned short)(r>>16);
}
static __device__ __forceinline__ float bf2f(unsigned short h){ return __uint_as_float(((unsigned)h)<<16); }

// chunk-local permuted position for k' (0..31)
static __device__ __forceinline__ int zpos(int kq){
  return (kq&3) + (((kq>>4)&1)<<2) + (((kq>>2)&3)<<3);
}

// fused LSTM cell: 5 exp + 2 rcp
static __device__ __forceinline__ float lstm_cell(float gi, float gf, float gg, float go, float& c){
  float ef = __expf(-gf), ei = __expf(-gi), eg = __expf(-2.0f*gg);
  float pN = c*(1.0f+ei)*(1.0f+eg) + (1.0f-eg)*(1.0f+ef);
  float pD = (1.0f+ef)*(1.0f+ei)*(1.0f+eg);
  float cc = pN * __builtin_amdgcn_rcpf(pD);
  c = cc;
  float eo = __expf(-go), ec = __expf(-2.0f*cc);
  return (1.0f-ec) * __builtin_amdgcn_rcpf((1.0f+eo)*(1.0f+ec));
}

static __device__ __forceinline__ void edge_sd(const int* __restrict__ ei, int e, int& s, int& d){
  if (e < EE){ s = ei[e]; d = ei[EE + e]; } else { s = e - EE; d = s; }
}

// ---------------- utility kernels ----------------
__global__ void kzero_int(int* __restrict__ p, int n){
  int i = blockIdx.x*256 + threadIdx.x;
  if (i < n) p[i] = 0;
}

// Pack weights into MFMA A-frag layout, rows permuted so C/D row = 4*unitLocal + gateType. (verified R9-R12)
__global__ void pack_weights(const float* __restrict__ Wih0, const float* __restrict__ Whh0,
                             const float* __restrict__ bih0, const float* __restrict__ bhh0,
                             const float* __restrict__ Wih1, const float* __restrict__ Whh1,
                             const float* __restrict__ bih1, const float* __restrict__ bhh1,
                             unsigned short* __restrict__ Wpk,
                             float* __restrict__ b0, float* __restrict__ b1){
  int idx = blockIdx.x*256 + threadIdx.x;
  if (idx < 49152){
    int fb = idx >> 9;            // (tl*3+ks)*2+h
    int h  = fb & 1;
    int t2 = fb >> 1;
    int ks = t2 % 3, tl = t2 / 3;
    int r  = idx & 511;
    int l  = r >> 3, j = r & 7;
    int pr = l & 15;
    int g  = (pr&3)*64 + tl*4 + (pr>>2);
    int k  = ks*32 + 4*(l>>4) + (j & 3) + 16*(j >> 2);
    float src = (k < 32) ? Wih0[g*32 + k] : Whh0[g*64 + (k - 32)];
    unsigned short hi = f2bf(src);
    Wpk[idx] = h ? f2bf(src - bf2f(hi)) : hi;
  } else if (idx < 114688){
    int idx2 = idx - 49152;
    int fb = idx2 >> 9;           // (tl*4+ks)*2+h
    int h  = fb & 1;
    int t2 = fb >> 1;
    int ks = t2 & 3, tl = t2 >> 2;
    int r  = idx2 & 511;
    int l  = r >> 3, j = r & 7;
    int pr = l & 15;
    int g  = (pr&3)*64 + tl*4 + (pr>>2);
    int k  = ks*32 + 4*(l>>4) + (j & 3) + 16*(j >> 2);
    float src = (k < 64) ? Wih1[g*64 + k] : Whh1[g*64 + (k - 64)];
    unsigned short hi = f2bf(src);
    Wpk[idx] = h ? f2bf(src - bf2f(hi)) : hi;
  } else {
    int m = idx - 114688;
    if (m < 256) b0[m] = bih0[m] + bhh0[m];
    else if (m < 512) b1[m-256] = bih1[m-256] + bhh1[m-256];
  }
}

// ---------------- CSR build (dst-indexed), parallel scan ----------------
__global__ void count_deg(const int* __restrict__ ei, int* __restrict__ deg){
  int e = blockIdx.x*256 + threadIdx.x;
  if (e >= ETOT) return;
  int s, d; edge_sd(ei, e, s, d);
  atomicAdd(deg + d, 1);
}

__global__ void scan_part(const int* __restrict__ deg, int* __restrict__ part){
  __shared__ int s[256];
  const int b = blockIdx.x, t = threadIdx.x;
  int v = (t < 250) ? deg[b*250 + t] : 0;
  s[t] = v; __syncthreads();
  for (int off=128; off>=1; off>>=1){ if (t<off) s[t]+=s[t+off]; __syncthreads(); }
  if (t==0) part[b] = s[0];
}

__global__ void scan_tops(int* __restrict__ part){
  if (threadIdx.x==0){
    int run=0;
    for (int i=0;i<SCB;i++){ int v=part[i]; part[i]=run; run+=v; }
  }
}

__global__ void scan_fill(const int* __restrict__ deg, const int* __restrict__ part,
                          int* __restrict__ indptr, int* __restrict__ cursor){
  __shared__ int s[256];
  const int b = blockIdx.x, t = threadIdx.x;
  int v = (t < 250) ? deg[b*250 + t] : 0;
  s[t] = v; __syncthreads();
  int val = v;
  for (int off=1; off<256; off<<=1){
    int add = (t>=off) ? s[t-off] : 0;
    __syncthreads();
    val += add; s[t] = val;
    __syncthreads();
  }
  int excl = val - v + part[b];
  if (t < 250){ indptr[b*250 + t] = excl; cursor[b*250 + t] = excl; }
  if (b == SCB-1 && t == 0) indptr[NN] = ETOT;
}

__global__ void scatter_edges(const int* __restrict__ ei, int* __restrict__ cursor, int* __restrict__ csr_src){
  int e = blockIdx.x*256 + threadIdx.x;
  if (e >= ETOT) return;
  int s, d; edge_sd(ei, e, s, d);
  int pos = atomicAdd(cursor + d, 1);
  csr_src[pos] = s;
}

// pin a 16B weight fragment into VGPRs
#define PIN_LOAD(dst, p) asm volatile( \
    "global_load_dwordx4 %0, %1, off\n\t" \
    "s_waitcnt vmcnt(0)" \
    : "=&v"(dst) : "v"(p))

// ---------------- MFMA split-bf16 2-layer LSTM (R12 structure + hoisted LDS bases) ----------------
__global__ __launch_bounds__(1024)
__attribute__((amdgpu_waves_per_eu(4, 4)))
void lstm_mfma(
    const float* __restrict__ x,
    const unsigned short* __restrict__ Wpk,
    const float* __restrict__ b0, const float* __restrict__ b1,
    float* __restrict__ h1out)
{
  __shared__ unsigned short Zc[NB*ZRW];   // 52.5 KB

  const int tid  = threadIdx.x;
  const int lane = tid & 63;
  const int w    = __builtin_amdgcn_readfirstlane(tid >> 6);   // 0..15
  const int ln15 = lane & 15;
  const int lq   = lane >> 4;                                  // 0..3
  const int gbase = blockIdx.x * NB;

  const bf16x8* wp = (const bf16x8*)Wpk;

  bf16x8 wA0h[3], wA0l[3], wA1h[4], wA1l[4];
#pragma unroll
  for (int ks=0; ks<3; ++ks){
    PIN_LOAD(wA0h[ks], wp + ((w*3+ks)*2+0)*64 + lane);
    PIN_LOAD(wA0l[ks], wp + ((w*3+ks)*2+1)*64 + lane);
  }
#pragma unroll
  for (int ks=0; ks<4; ++ks){
    PIN_LOAD(wA1h[ks], wp + 6144 + ((w*4+ks)*2+0)*64 + lane);
    PIN_LOAD(wA1l[ks], wp + 6144 + ((w*4+ks)*2+1)*64 + lane);
  }

  f32x4 bv0, bv1;
  {
    const int u = w*4 + lq;
#pragma unroll
    for (int j=0; j<4; ++j){ bv0[j] = b0[j*64+u]; bv1[j] = b1[j*64+u]; }
  }

  // hoisted per-GG LDS bases: read base (with lq fold) and write base (row only)
  const unsigned short* zrb[5];
  unsigned short* zwb[5];
#pragma unroll
  for (int GG=0; GG<5; ++GG){
    zrb[GG] = &Zc[(GG*16+ln15)*ZRW + lq*16];
    zwb[GG] = &Zc[(GG*16+ln15)*ZRW];
  }

  // H-write hi-columns for unit u = w*4+lq (lo at +8)
  const int colbase = ((w&3)<<4) + lq + (((w>>2)&1)<<2);
  const int uc0 = (1 + (w>>3))*64 + colbase;   // h0 chunk
  const int uc1 = (3 + (w>>3))*64 + colbase;   // h1 chunk

  // x staging: threads 0..639
  const int xn = tid >> 3;
  const int xk = (tid & 7) * 4;
  const int p0 = (((xk>>4)&1)<<2) + (((xk>>2)&3)<<3);
  const int xoff = ((p0>>3)<<4) + (p0&7);
  const float* xp = x + (size_t)(gbase + ((xn < NB) ? xn : 0))*(TT*INF_) + xk;
  unsigned short* xw = &Zc[xn*ZRW + xoff];
  const bool xth = (tid < 640);

#define XSTAGE(v) {                                                       \
    unsigned pkA, pkB, plA, plB;                                          \
    asm("v_cvt_pk_bf16_f32 %0,%1,%2":"=v"(pkA):"v"((v).x),"v"((v).y));    \
    asm("v_cvt_pk_bf16_f32 %0,%1,%2":"=v"(pkB):"v"((v).z),"v"((v).w));    \
    float l0_ = (v).x - __uint_as_float(pkA<<16);                         \
    float l1_ = (v).y - __uint_as_float(pkA & 0xffff0000u);               \
    float l2_ = (v).z - __uint_as_float(pkB<<16);                         \
    float l3_ = (v).w - __uint_as_float(pkB & 0xffff0000u);               \
    asm("v_cvt_pk_bf16_f32 %0,%1,%2":"=v"(plA):"v"(l0_),"v"(l1_));        \
    asm("v_cvt_pk_bf16_f32 %0,%1,%2":"=v"(plB):"v"(l2_),"v"(l3_));        \
    *(uint2*)(xw)     = make_uint2(pkA, pkB);                             \
    *(uint2*)(xw + 8) = make_uint2(plA, plB); }

  for (int i = tid; i < NB*ZRW/2; i += 1024) ((unsigned*)Zc)[i] = 0;
  __syncthreads();
  if (xth){
    float4 v = *(const float4*)xp;
    XSTAGE(v);
  }
  __syncthreads();

  float c0[5], c1[5];
#pragma unroll
  for (int i=0;i<5;i++){ c0[i]=0.f; c1[i]=0.f; }
  f32x4 aL1[5];

#define MF(acc, A, B) acc = __builtin_amdgcn_mfma_f32_16x16x32_bf16((A),(B),(acc),0,0,0)

#define WPAIR(ha, hb, GA, GB, colh) {                                     \
    unsigned pk_, pl_;                                                    \
    asm("v_cvt_pk_bf16_f32 %0,%1,%2":"=v"(pk_):"v"(ha),"v"(hb));          \
    float la_ = (ha) - __uint_as_float(pk_<<16);                          \
    float lb_ = (hb) - __uint_as_float(pk_ & 0xffff0000u);                \
    asm("v_cvt_pk_bf16_f32 %0,%1,%2":"=v"(pl_):"v"(la_),"v"(lb_));        \
    zwb[GA][(colh)]     = (unsigned short)pk_;                            \
    zwb[GB][(colh)]     = (unsigned short)(pk_>>16);                      \
    zwb[GA][(colh) + 8] = (unsigned short)pl_;                            \
    zwb[GB][(colh) + 8] = (unsigned short)(pl_>>16); }

#define WSINGLE(hv, GG, colh) {                                           \
    const unsigned short _hh = f2bf(hv);                                  \
    zwb[GG][(colh)]     = _hh;                                            \
    zwb[GG][(colh) + 8] = f2bf((hv) - bf2f(_hh)); }

#define CHUNK(ACCS, CK, WH, WL)                                           \
    _Pragma("unroll")                                                     \
    for (int GG=0; GG<5; ++GG){                                           \
      const bf16x8 zh = *(const bf16x8*)(zrb[GG] + (CK)*64);              \
      const bf16x8 zl = *(const bf16x8*)(zrb[GG] + (CK)*64 + 8);          \
      MF(ACCS[GG], WH, zh); MF(ACCS[GG], WH, zl); MF(ACCS[GG], WL, zh);   \
    }

  for (int t=0; t<TT; ++t){
    // ====== P1: x(t+1) load issue; L0 chunk0; L1-cells(t-1)->H1; L0 chunks 1,2 ======
    float4 xv;
    const bool dox = xth && (t+1 < TT);
    if (dox) xv = *(const float4*)(xp + (size_t)(t+1)*INF_);

    f32x4 aL0[5];
#pragma unroll
    for (int GG=0; GG<5; ++GG) aL0[GG] = bv0;

    CHUNK(aL0, 0, wA0h[0], wA0l[0]);          // x slab

    if (t > 0){
      float h0_ = lstm_cell(aL1[0][0], aL1[0][1], aL1[0][2], aL1[0][3], c1[0]);
      float h1_ = lstm_cell(aL1[1][0], aL1[1][1], aL1[1][2], aL1[1][3], c1[1]);
      float h2_ = lstm_cell(aL1[2][0], aL1[2][1], aL1[2][2], aL1[2][3], c1[2]);
      float h3_ = lstm_cell(aL1[3][0], aL1[3][1], aL1[3][2], aL1[3][3], c1[3]);
      float h4_ = lstm_cell(aL1[4][0], aL1[4][1], aL1[4][2], aL1[4][3], c1[4]);
      WPAIR(h0_, h1_, 0, 1, uc1); WPAIR(h2_, h3_, 2, 3, uc1); WSINGLE(h4_, 4, uc1);
    }

    CHUNK(aL0, 1, wA0h[1], wA0l[1]);          // h0 slab a
    CHUNK(aL0, 2, wA0h[2], wA0l[2]);          // h0 slab b
    __syncthreads();

    // ====== P2: L1 chunks 3,4 (H1(t-1)); L0-cells->H0 + x(t+1) write ======
#pragma unroll
    for (int GG=0; GG<5; ++GG) aL1[GG] = bv1;

    CHUNK(aL1, 3, wA1h[2], wA1l[2]);          // h1 slab a

    {
      float h0_ = lstm_cell(aL0[0][0], aL0[0][1], aL0[0][2], aL0[0][3], c0[0]);
      float h1_ = lstm_cell(aL0[1][0], aL0[1][1], aL0[1][2], aL0[1][3], c0[1]);
      float h2_ = lstm_cell(aL0[2][0], aL0[2][1], aL0[2][2], aL0[2][3], c0[2]);
      float h3_ = lstm_cell(aL0[3][0], aL0[3][1], aL0[3][2], aL0[3][3], c0[3]);
      float h4_ = lstm_cell(aL0[4][0], aL0[4][1], aL0[4][2], aL0[4][3], c0[4]);
      WPAIR(h0_, h1_, 0, 1, uc0); WPAIR(h2_, h3_, 2, 3, uc0); WSINGLE(h4_, 4, uc0);
    }
    if (dox) XSTAGE(xv);

    CHUNK(aL1, 4, wA1h[3], wA1l[3]);          // h1 slab b
    __syncthreads();

    // ====== P3: L1 chunks 1,2 (H0 just written) — no trailing barrier ======
    CHUNK(aL1, 1, wA1h[0], wA1l[0]);
    CHUNK(aL1, 2, wA1h[1], wA1l[1]);
  }

  // final L1 cells -> H1
  {
    float h0_ = lstm_cell(aL1[0][0], aL1[0][1], aL1[0][2], aL1[0][3], c1[0]);
    float h1_ = lstm_cell(aL1[1][0], aL1[1][1], aL1[1][2], aL1[1][3], c1[1]);
    float h2_ = lstm_cell(aL1[2][0], aL1[2][1], aL1[2][2], aL1[2][3], c1[2]);
    float h3_ = lstm_cell(aL1[3][0], aL1[3][1], aL1[3][2], aL1[3][3], c1[3]);
    float h4_ = lstm_cell(aL1[4][0], aL1[4][1], aL1[4][2], aL1[4][3], c1[4]);
    WPAIR(h0_, h1_, 0, 1, uc1); WPAIR(h2_, h3_, 2, 3, uc1); WSINGLE(h4_, 4, uc1);
  }
  __syncthreads();

  // epilogue: coalesced h1 write
  for (int o = tid; o < NB*64; o += 1024){
    const int n = o >> 6, u = o & 63;
    const int p = zpos(u & 31);
    const int ch = (3 + (u>>5))*64 + ((p>>3)<<4) + (p&7);
    h1out[(size_t)(gbase+n)*64 + u] = bf2f(Zc[n*ZRW + ch]) + bf2f(Zc[n*ZRW + ch + 8]);
  }
#undef MF
#undef WPAIR
#undef WSINGLE
#undef CHUNK
#undef XSTAGE
}

// ---------------- GAT layer 1 prep: 32 nodes/block ----------------
__global__ __launch_bounds__(256) void gat1_prep(const float* __restrict__ h1, const float* __restrict__ W,
  const float* __restrict__ as_, const float* __restrict__ ad_,
  float* __restrict__ xh, float* __restrict__ als, float* __restrict__ ald)
{
  __shared__ float hs[32][64];
  const int nb0 = blockIdx.x * 32;
  const int o  = threadIdx.x;
  const int q  = o >> 6, u = o & 63;
  for (int i = o; i < 2048; i += 256){
    hs[i>>6][i&63] = h1[(size_t)(nb0 + (i>>6))*64 + (i&63)];
  }
  __syncthreads();
  float acc[32];
#pragma unroll
  for (int nd=0; nd<32; ++nd) acc[nd] = 0.f;
  for (int k=0; k<64; ++k){
    const float wv = W[k*256 + o];
#pragma unroll
    for (int nd=0; nd<32; ++nd) acc[nd] = fmaf(hs[nd][k], wv, acc[nd]);
  }
  const float asv = as_[o], adv = ad_[o];
#pragma unroll
  for (int nd=0; nd<32; ++nd){
    xh[(size_t)(nb0+nd)*256 + o] = acc[nd];
    float ps = acc[nd] * asv;
    float pd = acc[nd] * adv;
#pragma unroll
    for (int off=32; off>=1; off>>=1){ ps += __shfl_xor(ps, off); pd += __shfl_xor(pd, off); }
    if (u == 0){ als[(nb0+nd)*4 + q] = ps; ald[(nb0+nd)*4 + q] = pd; }
  }
}

// ---------------- GAT1 gather + fused epilogue ----------------
__global__ __launch_bounds__(256) void gat1_gather(
  const int* __restrict__ indptr, const int* __restrict__ csr_src,
  const float* __restrict__ als, const float* __restrict__ ald,
  const float* __restrict__ xh,  const float* __restrict__ b1g,
  const float* __restrict__ w2,  const float* __restrict__ as2, const float* __restrict__ ad2,
  float* __restrict__ xh2, float* __restrict__ a2s, float* __restrict__ a2d)
{
  const int d = blockIdx.x*4 + (threadIdx.x >> 6);
  const int lane = threadIdx.x & 63;
  if (d >= NN) return;
  const int p0 = indptr[d], p1 = indptr[d+1];

  float aldv[4];
#pragma unroll
  for (int q=0;q<4;q++) aldv[q] = ald[d*4+q];

  float mx[4];
#pragma unroll
  for (int q=0;q<4;q++) mx[q] = -3.4e38f;
  for (int e=p0+lane; e<p1; e+=64){
    int s = csr_src[e];
#pragma unroll
    for (int q=0;q<4;q++){
      float ev = lrelu(als[s*4+q] + aldv[q]);
      mx[q] = fmaxf(mx[q], ev);
    }
  }
#pragma unroll
  for (int off=32; off>=1; off>>=1){
#pragma unroll
    for (int q=0;q<4;q++) mx[q] = fmaxf(mx[q], __shfl_xor(mx[q], off));
  }

  const int q = lane >> 4;
  const float mq = mx[q];
  const float aldq = aldv[q];
  float ax=0.f, ay=0.f, az=0.f, aw=0.f, den=0.f;
  int s_next = (p0 < p1) ? csr_src[p0] : 0;
  for (int e=p0; e<p1; ++e){
    const int s = s_next;
    if (e+1 < p1) s_next = csr_src[e+1];
    float ev = lrelu(als[s*4+q] + aldq);
    float ex = __expf(ev - mq);
    den += ex;
    float4 v = *(const float4*)(xh + (size_t)s*256 + lane*4);
    ax = fmaf(ex, v.x, ax); ay = fmaf(ex, v.y, ay);
    az = fmaf(ex, v.z, az); aw = fmaf(ex, v.w, aw);
  }
  const float rr = 1.0f/(den + 1e-16f);
  const int o = lane*4;
  float v0 = ax*rr + b1g[o+0];
  float v1 = ay*rr + b1g[o+1];
  float v2 = az*rr + b1g[o+2];
  float v3 = aw*rr + b1g[o+3];
  v0 = v0>0.f?v0:0.f; v1 = v1>0.f?v1:0.f; v2 = v2>0.f?v2:0.f; v3 = v3>0.f?v3:0.f;
  float part = v0*w2[o+0] + v1*w2[o+1] + v2*w2[o+2] + v3*w2[o+3];
#pragma unroll
  for (int off=32; off>=1; off>>=1) part += __shfl_xor(part, off);
  if (lane == 0){
    xh2[d] = part;
    a2s[d] = part * as2[0];
    a2d[d] = part * ad2[0];
  }
}

// ---------------- GAT2 gather ----------------
__global__ __launch_bounds__(256) void gat2_gather(
  const int* __restrict__ indptr, const int* __restrict__ csr_src,
  const float* __restrict__ a2s, const float* __restrict__ a2d,
  const float* __restrict__ xh2, const float* __restrict__ b2,
  float* __restrict__ out)
{
  const int d = blockIdx.x*4 + (threadIdx.x >> 6);
  const int lane = threadIdx.x & 63;
  if (d >= NN) return;
  const int p0 = indptr[d], p1 = indptr[d+1];
  const float add = a2d[d];

  float mx = -3.4e38f;
  for (int e=p0+lane; e<p1; e+=64){
    int s = csr_src[e];
    mx = fmaxf(mx, lrelu(a2s[s] + add));
  }
#pragma unroll
  for (int off=32; off>=1; off>>=1) mx = fmaxf(mx, __shfl_xor(mx, off));

  float den = 0.f, num = 0.f;
  for (int e=p0+lane; e<p1; e+=64){
    int s = csr_src[e];
    float ev = lrelu(a2s[s] + add);
    float ex = __expf(ev - mx);
    den += ex;
    num = fmaf(ex, xh2[s], num);
  }
#pragma unroll
  for (int off=32; off>=1; off>>=1){ den += __shfl_xor(den, off); num += __shfl_xor(num, off); }
  if (lane == 0) out[d] = num/(den + 1e-16f) + b2[0];
}

// ---------------- launcher ----------------
extern "C" void kernel_launch(void* const* d_in, const int* in_sizes, int n_in,
                              void* d_out, int out_size, void* d_ws, size_t ws_size,
                              hipStream_t stream)
{
  const float* x    = (const float*)d_in[0];
  const int*   ei   = (const int*)d_in[1];
  const float* Wih0 = (const float*)d_in[2];
  const float* Whh0 = (const float*)d_in[3];
  const float* bih0 = (const float*)d_in[4];
  const float* bhh0 = (const float*)d_in[5];
  const float* Wih1 = (const float*)d_in[6];
  const float* Whh1 = (const float*)d_in[7];
  const float* bih1 = (const float*)d_in[8];
  const float* bhh1 = (const float*)d_in[9];
  const float* g1w  = (const float*)d_in[10];
  const float* g1as = (const float*)d_in[11];
  const float* g1ad = (const float*)d_in[12];
  const float* g1b  = (const float*)d_in[13];
  const float* g2w  = (const float*)d_in[14];
  const float* g2as = (const float*)d_in[15];
  const float* g2ad = (const float*)d_in[16];
  const float* g2b  = (const float*)d_in[17];

  float* ws  = (float*)d_ws;
  unsigned short* Wpk = (unsigned short*)ws;   // 114688 shorts = 57344 f32 slots
  float* b0  = ws + 57344;            // 256
  float* b1  = b0 + 256;              // 256
  float* h1  = b1 + 256;              // 20000*64
  float* xh  = h1 + 1280000;          // 20000*256
  float* als = xh + 5120000;          // 80000
  float* ald = als + 80000;           // 80000
  float* xh2 = ald + 80000;           // 20000
  float* a2s = xh2 + 20000;           // 20000
  float* a2d = a2s + 20000;           // 20000
  int*   deg    = (int*)(a2d + 20000);   // 20000
  int*   indptr = deg + 20000;           // 20001
  int*   cursor = indptr + 20001;        // 20000
  int*   csr    = cursor + 20000;        // 340000
  int*   spart  = csr + 340000;          // 80

  kzero_int<<<(NN+255)/256, 256, 0, stream>>>(deg, NN);
  pack_weights<<<450, 256, 0, stream>>>(Wih0,Whh0,bih0,bhh0,Wih1,Whh1,bih1,bhh1,Wpk,b0,b1);
  count_deg<<<(ETOT+255)/256, 256, 0, stream>>>(ei, deg);
  scan_part<<<SCB, 256, 0, stream>>>(deg, spart);
  scan_tops<<<1, 64, 0, stream>>>(spart);
  scan_fill<<<SCB, 256, 0, stream>>>(deg, spart, indptr, cursor);
  scatter_edges<<<(ETOT+255)/256, 256, 0, stream>>>(ei, cursor, csr);
  lstm_mfma<<<250, 1024, 0, stream>>>(x, Wpk, b0, b1, h1);
  gat1_prep<<<NN/32, 256, 0, stream>>>(h1, g1w, g1as, g1ad, xh, als, ald);
  gat1_gather<<<(NN+3)/4, 256, 0, stream>>>(indptr, csr, als, ald, xh, g1b, g2w, g2as, g2ad, xh2, a2s, a2d);
  gat2_gather<<<(NN+3)/4, 256, 0, stream>>>(indptr, csr, a2s, a2d, xh2, g2b, (float*)d_out);
}